// Round 5
// baseline (716.366 us; speedup 1.0000x reference)
//
#include <hip/hip_runtime.h>
#include <hip/hip_cooperative_groups.h>
#include <cmath>

namespace cg = cooperative_groups;

// Temporal Contrast Enhancement — cooperative single-kernel pipeline.
// Same phase structure as the proven 7-kernel version (comp_d, scan_d,
// comp_a, scan_a, comp_e, scan_e, final) but kernel boundaries are replaced
// by grid.sync() in ONE cooperative launch. R4's hand-rolled spin-lookback
// stalled 90% on cross-XCD coherency traffic; grid.sync does the same
// synchronization through the proper barrier path. Fallback: if the
// cooperative launch is rejected, run the identical phases as 7 kernels.

static constexpr int   kT   = 88200;
static constexpr float kSR  = 44100.0f;
static constexpr int   kS   = 40;             // samples/chunk, divides kT
static constexpr int   kS4  = kS / 4;         // 10 float4 per chunk
static constexpr int   kNC  = kT / kS;        // 2205 chunks/series
static constexpr int   kCT  = 256;            // chunks per virtual tile
static constexpr int   kPad = kS + 4;         // padded LDS chunk stride (44)

struct EnvP { float ad, bd, aa, ba, nuamp, reg; };

__device__ __forceinline__ EnvP make_params(const float* tauA, const float* tauD,
                                            const float* nu, const float* dbreg) {
  EnvP p;
  float td = fminf(fmaxf(tauD[0], 1.0f), 100.0f);
  td = fminf(fmaxf(td, 0.1f), 1000.0f) * 0.001f;
  float ta = fminf(fmaxf(tauA[0], 1.0f), 100.0f);
  ta = fminf(fmaxf(ta, 0.1f), 1000.0f) * 0.001f;
  p.ad = expf(-1.0f / (td * kSR));
  p.aa = expf(-1.0f / (ta * kSR));
  p.bd = 1.0f - p.ad;
  p.ba = 1.0f - p.aa;
  p.nuamp = exp10f(fminf(fmaxf(nu[0],    -60.0f),   0.0f) * 0.05f);
  p.reg   = exp10f(fminf(fmaxf(dbreg[0], -120.0f), -60.0f) * 0.05f);
  return p;
}

// ---- one virtual tile (256 consecutive chunks) of a comp/final phase ------
// MODE: 0=comp_d  1=comp_a  2=comp_e  3=final
template <int MODE>
__device__ __forceinline__ void comp_tile(int g, int t,
    const float* __restrict__ x, float* lds, const EnvP& p,
    const float* __restrict__ Yd, const float* __restrict__ Ya,
    const float* __restrict__ Ye,
    float* __restrict__ O0, float* __restrict__ O1) {
  const size_t tileBase = (size_t)g * (kCT * kS);
  const float4* xg = reinterpret_cast<const float4*>(x + tileBase);
  // stage: coalesced global -> padded LDS (kCT*kS/4/256 == kS4 iters)
#pragma unroll
  for (int i = 0; i < kS4; ++i) {
    int idx = t + i * 256;
    float4 v = xg[idx];
    int chunk = idx / kS4;
    int off   = (idx - chunk * kS4) * 4;
    *reinterpret_cast<float4*>(&lds[chunk * kPad + off]) = v;
  }
  __syncthreads();
  const int gchunk = g * kCT + t;
  float* my = &lds[t * kPad];

  if (MODE == 0) {
    float A = -INFINITY, B = 0.f;
#pragma unroll 2
    for (int i = 0; i < kS4; ++i) {
      float4 v = *reinterpret_cast<const float4*>(&my[4 * i]);
      float vv[4] = {v.x, v.y, v.z, v.w};
#pragma unroll
      for (int j = 0; j < 4; ++j) {
        float xa = fabsf(vv[j]);
        float bx = p.bd * xa;
        A = fmaxf(xa, fmaf(p.ad, A, bx));
        B = fmaf(p.ad, B, bx);
      }
    }
    O0[gchunk] = A; O1[gchunk] = B;
  } else if (MODE == 1) {
    float yd = Yd[gchunk];
    float A = INFINITY, B = 0.f;
#pragma unroll 2
    for (int i = 0; i < kS4; ++i) {
      float4 v = *reinterpret_cast<const float4*>(&my[4 * i]);
      float vv[4] = {v.x, v.y, v.z, v.w};
#pragma unroll
      for (int j = 0; j < 4; ++j) {
        float xa = fabsf(vv[j]);
        yd = fmaxf(xa, fmaf(p.ad, yd, p.bd * xa));
        float by = p.ba * yd;
        A = fminf(yd, fmaf(p.aa, A, by));
        B = fmaf(p.aa, B, by);
      }
    }
    O0[gchunk] = A; O1[gchunk] = B;
  } else if (MODE == 2) {
    float yd = Yd[gchunk], ya = Ya[gchunk];
    float A = -INFINITY, B = 0.f;
#pragma unroll 2
    for (int i = 0; i < kS4; ++i) {
      float4 v = *reinterpret_cast<const float4*>(&my[4 * i]);
      float vv[4] = {v.x, v.y, v.z, v.w};
#pragma unroll
      for (int j = 0; j < 4; ++j) {
        float xa = fabsf(vv[j]);
        yd = fmaxf(xa, fmaf(p.ad, yd, p.bd * xa));
        ya = fminf(yd, fmaf(p.aa, ya, p.ba * yd));
        float et = fmaxf((yd - ya) - p.nuamp, 0.0f);
        float bx = p.bd * et;
        A = fmaxf(et, fmaf(p.ad, A, bx));
        B = fmaf(p.ad, B, bx);
      }
    }
    O0[gchunk] = A; O1[gchunk] = B;
  } else {
    float yd = Yd[gchunk], ya = Ya[gchunk], ye = Ye[gchunk];
#pragma unroll 2
    for (int i = 0; i < kS4; ++i) {
      float4 v = *reinterpret_cast<const float4*>(&my[4 * i]);
      float vv[4] = {v.x, v.y, v.z, v.w};
      float oo[4];
#pragma unroll
      for (int j = 0; j < 4; ++j) {
        float xa = fabsf(vv[j]);
        yd = fmaxf(xa, fmaf(p.ad, yd, p.bd * xa));
        ya = fminf(yd, fmaf(p.aa, ya, p.ba * yd));
        float et = fmaxf((yd - ya) - p.nuamp, 0.0f);
        ye = fmaxf(et, fmaf(p.ad, ye, p.bd * et));
        oo[j] = vv[j] * (et / (ye + p.reg));
      }
      *reinterpret_cast<float4*>(&my[4 * i]) = make_float4(oo[0], oo[1], oo[2], oo[3]);
    }
    __syncthreads();
    float4* og = reinterpret_cast<float4*>(O0 + tileBase);
#pragma unroll
    for (int i = 0; i < kS4; ++i) {
      int idx = t + i * 256;
      int chunk = idx / kS4;
      int off   = (idx - chunk * kS4) * 4;
      og[idx] = *reinterpret_cast<const float4*>(&lds[chunk * kPad + off]);
    }
  }
  __syncthreads();   // LDS reused by next tile / next phase
}

// ---- per-series scan of chunk transfers (one 256-thread block) ------------
template <int ATTACK>
__device__ __forceinline__ void scan_series(const float* __restrict__ A,
                                            const float* __restrict__ B,
                                            float* __restrict__ Y,
                                            int s, int t, const EnvP& p,
                                            float* sA, float* sB, float* sG) {
  constexpr int NC  = kNC;
  constexpr int CPT = (NC + 255) / 256;     // 9
  const float alpha = ATTACK ? p.aa : p.ad;
  const float ID_A  = ATTACK ? INFINITY : -INFINITY;
  long base = (long)s * NC;
  float gS = powf(alpha, (float)kS);

  float ca[CPT], cb[CPT];
  float a = ID_A, b = 0.f, g = 1.f;
#pragma unroll
  for (int k = 0; k < CPT; ++k) {
    int c = t * CPT + k;
    if (c < NC) { ca[k] = A[base + c]; cb[k] = B[base + c]; }
    else        { ca[k] = ID_A;        cb[k] = 0.f; }
    float cg = (c < NC) ? gS : 1.f;
    float na = ATTACK ? fminf(ca[k], fmaf(cg, a, cb[k]))
                      : fmaxf(ca[k], fmaf(cg, a, cb[k]));
    b = fmaf(cg, b, cb[k]);
    g = cg * g;
    a = na;
  }
  sA[t] = a; sB[t] = b; sG[t] = g;
  __syncthreads();
#pragma unroll
  for (int d = 1; d < 256; d <<= 1) {
    float pa = 0.f, pb = 0.f, pg = 0.f;
    if (t >= d) { pa = sA[t - d]; pb = sB[t - d]; pg = sG[t - d]; }
    __syncthreads();
    if (t >= d) {
      float na = ATTACK ? fminf(a, fmaf(g, pa, b)) : fmaxf(a, fmaf(g, pa, b));
      b = fmaf(g, pb, b);
      g = g * pg;
      a = na;
      sA[t] = a; sB[t] = b; sG[t] = g;
    }
    __syncthreads();
  }
  float ea, eb;
  if (t == 0) { ea = ID_A; eb = 0.f; }
  else        { ea = sA[t - 1]; eb = sB[t - 1]; }
#pragma unroll
  for (int k = 0; k < CPT; ++k) {
    int c = t * CPT + k;
    if (c >= NC) break;
    Y[base + c] = ATTACK ? fminf(ea, eb) : fmaxf(ea, eb);   // y0 = 0
    float na = ATTACK ? fminf(ca[k], fmaf(gS, ea, cb[k]))
                      : fmaxf(ca[k], fmaf(gS, ea, cb[k]));
    eb = fmaf(gS, eb, cb[k]);
    ea = na;
  }
  __syncthreads();
}

// ================= cooperative all-in-one kernel =================
__global__ __launch_bounds__(256, 3)
void k_coop(const float* __restrict__ x,
            const float* tauA, const float* tauD,
            const float* nu, const float* dbreg,
            float* __restrict__ out,
            float* __restrict__ A, float* __restrict__ B,
            float* __restrict__ Yd, float* __restrict__ Ya,
            float* __restrict__ Ye,
            int nseries, int ntiles) {
  cg::grid_group grid = cg::this_grid();
  __shared__ float lds[kCT * kPad];
  __shared__ float sA[256], sB[256], sG[256];
  const int t = threadIdx.x;
  const EnvP p = make_params(tauA, tauD, nu, dbreg);

  for (int g = blockIdx.x; g < ntiles; g += gridDim.x)
    comp_tile<0>(g, t, x, lds, p, nullptr, nullptr, nullptr, A, B);
  grid.sync();
  if (blockIdx.x < nseries) scan_series<0>(A, B, Yd, blockIdx.x, t, p, sA, sB, sG);
  grid.sync();
  for (int g = blockIdx.x; g < ntiles; g += gridDim.x)
    comp_tile<1>(g, t, x, lds, p, Yd, nullptr, nullptr, A, B);
  grid.sync();
  if (blockIdx.x < nseries) scan_series<1>(A, B, Ya, blockIdx.x, t, p, sA, sB, sG);
  grid.sync();
  for (int g = blockIdx.x; g < ntiles; g += gridDim.x)
    comp_tile<2>(g, t, x, lds, p, Yd, Ya, nullptr, A, B);
  grid.sync();
  if (blockIdx.x < nseries) scan_series<0>(A, B, Ye, blockIdx.x, t, p, sA, sB, sG);
  grid.sync();
  for (int g = blockIdx.x; g < ntiles; g += gridDim.x)
    comp_tile<3>(g, t, x, lds, p, Yd, Ya, Ye, out, nullptr);
}

// ================= fallback: same phases as 7 kernels =================
template <int MODE>
__global__ __launch_bounds__(256)
void k_pass(const float* __restrict__ x,
            const float* tauA, const float* tauD,
            const float* nu, const float* dbreg,
            const float* __restrict__ Yd, const float* __restrict__ Ya,
            const float* __restrict__ Ye,
            float* __restrict__ O0, float* __restrict__ O1) {
  __shared__ float lds[kCT * kPad];
  EnvP p = make_params(tauA, tauD, nu, dbreg);
  comp_tile<MODE>(blockIdx.x, threadIdx.x, x, lds, p, Yd, Ya, Ye, O0, O1);
}

template <int ATTACK>
__global__ __launch_bounds__(256)
void k_scan(const float* __restrict__ A, const float* __restrict__ B,
            float* __restrict__ Y,
            const float* tauA, const float* tauD,
            const float* nu, const float* dbreg) {
  __shared__ float sA[256], sB[256], sG[256];
  EnvP p = make_params(tauA, tauD, nu, dbreg);
  scan_series<ATTACK>(A, B, Y, blockIdx.x, threadIdx.x, p, sA, sB, sG);
}

extern "C" void kernel_launch(void* const* d_in, const int* in_sizes, int n_in,
                              void* d_out, int out_size, void* d_ws, size_t ws_size,
                              hipStream_t stream) {
  const float* x     = (const float*)d_in[0];
  const float* tauA  = (const float*)d_in[1];
  const float* tauD  = (const float*)d_in[2];
  const float* nu    = (const float*)d_in[3];
  const float* dbreg = (const float*)d_in[4];
  float* out = (float*)d_out;

  int nseries = in_sizes[0] / kT;           // 256
  int nch     = nseries * kNC;              // 564480
  int ntiles  = nch / kCT;                  // 2205

  float* wsf = (float*)d_ws;
  float* A  = wsf;
  float* B  = wsf + (size_t)nch;
  float* Yd = wsf + (size_t)2 * nch;
  float* Ya = wsf + (size_t)3 * nch;
  float* Ye = wsf + (size_t)4 * nch;

  // Size the cooperative grid to guaranteed co-residency.
  int occ = 0;
  hipOccupancyMaxActiveBlocksPerMultiprocessor(&occ, k_coop, 256, 0);
  if (occ < 1) occ = 1;
  int numCU = 256;
  hipDeviceProp_t prop;
  int dev = 0;
  if (hipGetDevice(&dev) == hipSuccess &&
      hipGetDeviceProperties(&prop, dev) == hipSuccess)
    numCU = prop.multiProcessorCount;
  int grid = occ * numCU;
  if (grid > ntiles) grid = ntiles;
  if (grid < nseries) grid = nseries;       // scans need >= nseries blocks

  void* args[] = {(void*)&x, (void*)&tauA, (void*)&tauD, (void*)&nu,
                  (void*)&dbreg, (void*)&out, (void*)&A, (void*)&B,
                  (void*)&Yd, (void*)&Ya, (void*)&Ye,
                  (void*)&nseries, (void*)&ntiles};
  hipError_t err = hipLaunchCooperativeKernel((const void*)k_coop,
                                              dim3(grid), dim3(256),
                                              args, 0, stream);
  if (err != hipSuccess) {
    // Fallback: identical phases as separate kernels (kernel-boundary sync).
    k_pass<0><<<ntiles, 256, 0, stream>>>(x, tauA, tauD, nu, dbreg, nullptr, nullptr, nullptr, A, B);
    k_scan<0><<<nseries, 256, 0, stream>>>(A, B, Yd, tauA, tauD, nu, dbreg);
    k_pass<1><<<ntiles, 256, 0, stream>>>(x, tauA, tauD, nu, dbreg, Yd, nullptr, nullptr, A, B);
    k_scan<1><<<nseries, 256, 0, stream>>>(A, B, Ya, tauA, tauD, nu, dbreg);
    k_pass<2><<<ntiles, 256, 0, stream>>>(x, tauA, tauD, nu, dbreg, Yd, Ya, nullptr, A, B);
    k_scan<0><<<nseries, 256, 0, stream>>>(A, B, Ye, tauA, tauD, nu, dbreg);
    k_pass<3><<<ntiles, 256, 0, stream>>>(x, tauA, tauD, nu, dbreg, Yd, Ya, Ye, out, nullptr);
  }
}